// Round 6
// baseline (854.840 us; speedup 1.0000x reference)
//
#include <hip/hip_runtime.h>
#include <stdint.h>

typedef unsigned short u16;
typedef __bf16 bf16t;
typedef bf16t bf16x8 __attribute__((ext_vector_type(8)));
typedef float f32x4 __attribute__((ext_vector_type(4)));
typedef unsigned long long ull;

#define NROWS 100000
#define DD 512
#define QD 128
#define KSEL 20000
#define NB 1563   // ceil(100000/64)
#define NBINS 4096

// ---------- helpers ----------
__device__ __forceinline__ uint32_t fmono(float x){
  uint32_t u = __float_as_uint(x);
  return (u & 0x80000000u) ? ~u : (u | 0x80000000u);
}
__device__ __forceinline__ float finv(uint32_t k){  // inverse of fmono
  uint32_t u = (k & 0x80000000u) ? (k & 0x7fffffffu) : ~k;
  return __uint_as_float(u);
}
__device__ __forceinline__ u16 f2bf(float x){  // RNE float->bf16 bits
  uint32_t u = __float_as_uint(x);
  u += 0x7fffu + ((u >> 16) & 1u);
  return (u16)(u >> 16);
}
__device__ __forceinline__ uint32_t pkbf(float a, float b){
  return (uint32_t)f2bf(a) | ((uint32_t)f2bf(b) << 16);
}

struct Scal {
  uint32_t keyT;
  float Z;
  uint32_t pad[14];
};

#define MFMA16(A,B,C) __builtin_amdgcn_mfma_f32_16x16x32_bf16(A,B,C,0,0,0)

// ---------- k_conv: fp32 weights -> bf16 chunk-format; zero hist / cmax ----------
// Chunk ci (0..143) = 128 output-rows x 32 K-cols, contiguous (4096 u16):
// elem = ci*4096 + r*32 + col.  Stage1: ci = nt*16+kc (Wl). Stage2: 64 + nt2*16+kc (Wq then Wv).
__global__ void k_conv(const float* __restrict__ Wl, const float* __restrict__ Wv,
                       const float* __restrict__ Wq, u16* __restrict__ wch,
                       uint32_t* __restrict__ hist, ull* __restrict__ cmax){
  int idx = blockIdx.x*256 + threadIdx.x;          // grid 2304*256 = 589824 exactly
  if (idx < NBINS) hist[idx] = 0u;
  if (idx == 0){ cmax[0] = 0ull; cmax[1] = 0ull; }
  int ci  = idx >> 12;
  int rem = idx & 4095;
  int r   = rem >> 5;
  int col = rem & 31;
  float v;
  if (ci < 64){
    int nt = ci >> 4, kc = ci & 15;
    v = Wl[(size_t)(nt*128 + r)*DD + kc*32 + col];
  } else {
    int c2 = ci - 64;
    int nt2 = c2 >> 4, kc = c2 & 15;
    if (nt2 == 0) v = Wq[(size_t)r*DD + kc*32 + col];
    else          v = Wv[(size_t)((nt2-1)*128 + r)*DD + kc*32 + col];
  }
  wch[idx] = f2bf(v);
}

// ---------- k_sel1: multi-block 12-bit histogram of fmono(preds) + c-argmax partials ----------
__global__ void k_sel1(const float* __restrict__ preds, const float* __restrict__ c,
                       uint32_t* __restrict__ hist, ull* __restrict__ cmax){
  __shared__ ull kr0[4], kr1[4];
  const int t = threadIdx.x;                // 256
  const int gid = blockIdx.x*256 + t;       // grid 256 blocks -> 65536 threads
  const int lane = t & 63;

  const float4* p4 = (const float4*)preds;
  for (int i = gid; i < 25000; i += 65536){
    float4 v = p4[i];
    atomicAdd(&hist[fmono(v.x) >> 20], 1u);
    atomicAdd(&hist[fmono(v.y) >> 20], 1u);
    atomicAdd(&hist[fmono(v.z) >> 20], 1u);
    atomicAdd(&hist[fmono(v.w) >> 20], 1u);
  }

  ull k0 = 0ull, k1 = 0ull;
  const float4* c4 = (const float4*)c;
  for (int i = gid; i < 50000; i += 65536){
    float4 v = c4[i];                       // rows 2i (x=c0,y=c1), 2i+1 (z=c0,w=c1)
    uint32_t r0 = 2u*i, r1 = 2u*i + 1u;
    ull a0 = ((ull)fmono(v.x) << 32) | (ull)(~r0);
    ull a1 = ((ull)fmono(v.z) << 32) | (ull)(~r1);
    ull b0 = ((ull)fmono(v.y) << 32) | (ull)(~r0);
    ull b1 = ((ull)fmono(v.w) << 32) | (ull)(~r1);
    if (a0 > k0) k0 = a0;
    if (a1 > k0) k0 = a1;
    if (b0 > k1) k1 = b0;
    if (b1 > k1) k1 = b1;
  }
  #pragma unroll
  for (int off = 32; off; off >>= 1){
    ull o0 = __shfl_xor(k0, off); if (o0 > k0) k0 = o0;
    ull o1 = __shfl_xor(k1, off); if (o1 > k1) k1 = o1;
  }
  if (lane == 0){ kr0[t >> 6] = k0; kr1[t >> 6] = k1; }
  __syncthreads();
  if (t == 0){
    ull m0 = kr0[0], m1 = kr1[0];
    #pragma unroll
    for (int w = 1; w < 4; ++w){
      if (kr0[w] > m0) m0 = kr0[w];
      if (kr1[w] > m1) m1 = kr1[w];
    }
    atomicMax(&cmax[0], m0);
    atomicMax(&cmax[1], m1);
  }
}

// ---------- k_prep2: one block — scan hist, exact keyT, Z ----------
#define CAND_CAP 8192
__launch_bounds__(1024)
__global__ void k_prep2(const float* __restrict__ preds,
                        const uint32_t* __restrict__ hist,
                        Scal* __restrict__ sc){
  __shared__ uint32_t cand[CAND_CAP];
  __shared__ uint32_t wsum[16], woff[16];
  __shared__ float zred[16];
  __shared__ uint32_t s_B, s_cumBelow, s_keyT, candN;
  const int t = threadIdx.x;
  const int lane = t & 63, wv = t >> 6;

  if (t == 0) candN = 0;

  // ---- parallel scan of 4096-bin histogram; find bucket containing rank KSEL ----
  const int b0 = t*4;
  uint4 hv = ((const uint4*)hist)[t];
  uint32_t local = hv.x + hv.y + hv.z + hv.w;
  uint32_t x = local;
  #pragma unroll
  for (int off = 1; off < 64; off <<= 1){
    uint32_t y = __shfl_up(x, off);
    if (lane >= off) x += y;
  }
  if (lane == 63) wsum[wv] = x;
  __syncthreads();
  if (t == 0){
    uint32_t cum = 0;
    for (int w = 0; w < 16; ++w){ woff[w] = cum; cum += wsum[w]; }
  }
  __syncthreads();
  uint32_t excl = x - local + woff[wv];       // exclusive prefix of this thread's 4 bins
  if (excl < KSEL && excl + local >= KSEL){   // unique crossing thread
    uint32_t cum = excl;
    uint32_t hh[4] = {hv.x, hv.y, hv.z, hv.w};
    #pragma unroll
    for (int b = 0; b < 4; ++b){
      if (cum + hh[b] >= KSEL){ s_B = (uint32_t)(b0 + b); s_cumBelow = cum; break; }
      cum += hh[b];
    }
  }
  __syncthreads();
  const uint32_t B = s_B;

  // ---- one pass over preds: sum exp over buckets > B; collect bucket-B candidates ----
  float sA = 0.f;
  const float4* p4 = (const float4*)preds;
  for (int i = t; i < 25000; i += 1024){
    float4 v = p4[i];
    float vv[4] = {v.x, v.y, v.z, v.w};
    #pragma unroll
    for (int e = 0; e < 4; ++e){
      uint32_t k = fmono(vv[e]);
      uint32_t bb = k >> 20;
      if (bb > B){
        sA += __expf(vv[e]);
      } else if (bb == B){
        uint32_t idx = atomicAdd(&candN, 1u);
        if (idx < CAND_CAP) cand[idx] = k;
      }
    }
  }
  #pragma unroll
  for (int off = 32; off; off >>= 1) sA += __shfl_xor(sA, off);
  if (lane == 0) zred[wv] = sA;
  __syncthreads();

  // ---- exact rank select among candidates (O(n^2), n ~ a thousand) ----
  const uint32_t n = candN < CAND_CAP ? candN : CAND_CAP;
  const uint32_t r = KSEL - s_cumBelow;       // 1-indexed rank within bucket
  for (uint32_t i = t; i < n; i += 1024){
    uint32_t ki = cand[i];
    uint32_t less = 0, eq = 0;
    for (uint32_t j = 0; j < n; ++j){
      uint32_t kj = cand[j];
      less += (kj < ki) ? 1u : 0u;
      eq   += (kj == ki) ? 1u : 0u;
    }
    if (less < r && r <= less + eq) s_keyT = ki;
  }
  __syncthreads();
  const uint32_t keyT = s_keyT;

  // ---- add exp of candidates strictly above keyT ----
  float sCA = 0.f;
  for (uint32_t i = t; i < n; i += 1024){
    uint32_t k = cand[i];
    if (k > keyT) sCA += __expf(finv(k));
  }
  #pragma unroll
  for (int off = 32; off; off >>= 1) sCA += __shfl_xor(sCA, off);
  if (lane == 0) zred[wv] += sCA;
  __syncthreads();
  if (t == 0){
    float Z = (float)KSEL;                    // exp(0)=1 for each of the KSEL zeroed entries
    for (int w = 0; w < 16; ++w) Z += zred[w];
    sc->keyT = keyT; sc->Z = Z;
  }
}

// ---------- k_prep3: 16 blocks — exact fp32 m_feats (f rows for the 2 argmax rows) ----------
__global__ void k_prep3(const float* __restrict__ preds, const float* __restrict__ feats,
                        const float* __restrict__ Wl, const float* __restrict__ bl,
                        const ull* __restrict__ cmax, const Scal* __restrict__ sc,
                        float* __restrict__ fmFw){
  __shared__ float fmX[2][512];
  __shared__ uint32_t s_mi[2];
  const int t = threadIdx.x;   // 256
  if (t < 2) s_mi[t] = ~(uint32_t)(cmax[t] & 0xffffffffull);
  __syncthreads();
  for (int i = t; i < 1024; i += 256){
    int j = i >> 9, col = i & 511;
    fmX[j][col] = feats[(size_t)s_mi[j]*DD + col];
  }
  __syncthreads();
  const int nn = blockIdx.x*32 + (t >> 3);
  const int h = t & 7;
  const float4* wr4 = (const float4*)(Wl + (size_t)nn*DD + h*64);
  const float4* x04 = (const float4*)(&fmX[0][h*64]);
  const float4* x14 = (const float4*)(&fmX[1][h*64]);
  float a0 = 0.f, a1 = 0.f;
  #pragma unroll
  for (int k = 0; k < 16; ++k){
    float4 w = wr4[k], u = x04[k], v = x14[k];
    a0 += u.x*w.x + u.y*w.y + u.z*w.z + u.w*w.w;
    a1 += v.x*w.x + v.y*w.y + v.z*w.z + v.w*w.w;
  }
  a0 += __shfl_xor(a0, 1); a0 += __shfl_xor(a0, 2); a0 += __shfl_xor(a0, 4);
  a1 += __shfl_xor(a1, 1); a1 += __shfl_xor(a1, 2); a1 += __shfl_xor(a1, 4);
  if (h == 0){
    uint32_t keyT = sc->keyT;
    float Z = sc->Z;
    float p0 = preds[s_mi[0]]; float q0 = (fmono(p0) <= keyT) ? 0.f : p0;
    float g0 = 1.f + __expf(q0) / Z;
    float p1 = preds[s_mi[1]]; float q1 = (fmono(p1) <= keyT) ? 0.f : p1;
    float g1 = 1.f + __expf(q1) / Z;
    float v0 = bl[nn] + g0*a0; fmFw[nn]       = v0 > 0.f ? v0 : 0.f;
    float v1 = bl[nn] + g1*a1; fmFw[512 + nn] = v1 > 0.f ? v1 : 0.f;
  }
}

// ---------- k_prep4: 2 blocks — q_max ----------
__global__ void k_prep4(const float* __restrict__ Wq, const float* __restrict__ bq,
                        const float* __restrict__ fmFw, float* __restrict__ qmv){
  __shared__ float xs[512];
  const int t = threadIdx.x;   // 256
  const int j = blockIdx.x;
  for (int i = t; i < 512; i += 256) xs[i] = fmFw[j*512 + i];
  __syncthreads();
  const int q = t >> 1, h = t & 1;
  const float4* wr4 = (const float4*)(Wq + (size_t)q*DD + h*256);
  const float4* x4  = (const float4*)(&xs[h*256]);
  float a = 0.f;
  #pragma unroll 4
  for (int k = 0; k < 64; ++k){
    float4 w = wr4[k], u = x4[k];
    a += u.x*w.x + u.y*w.y + u.z*w.z + u.w*w.w;
  }
  a += __shfl_xor(a, 1);
  if (h == 0) qmv[j*QD + q] = tanhf(bq[q] + a);
}

// ---------- k_fused v5: 512 threads / 8 waves, wave tile 32x32; barrier-free K-loop ----------
// Wave grid 2(wm) x 4(wn). B direct from L2 (2-deep chunk prefetch), A in swizzled LDS.
// LDS: AF 64KB + sred 2KB + EfL 0.5KB -> 2 blocks/CU, 16 waves/CU.
// Register demand cut vs v4: eR arrays replaced by EfL LDS reads (V epilogue).
// launch_bounds(512, 2): cap 256 total regs — allocator takes ~90, no spill (v4 spilled at cap 128).
__launch_bounds__(512, 2)
__global__ void k_fused(const float* __restrict__ feats, const float* __restrict__ preds,
                        const u16* __restrict__ wch,
                        const float* __restrict__ bl, const float* __restrict__ bv,
                        const float* __restrict__ bq, const float* __restrict__ qmv,
                        const Scal* __restrict__ sc,
                        float* __restrict__ gpart, float* __restrict__ gpartE,
                        float* __restrict__ Aout){
  __shared__ __align__(16) u16 AF[32768];    // [64][512]
  __shared__ __align__(16) float sred[512];  // [64 rows][2 j][4 wn]
  __shared__ __align__(16) float EfL[128];   // e-values [64 rows][2 j]
  const int tid = threadIdx.x;
  const int lane = tid & 63, quad = lane >> 4, l16 = lane & 15;
  const int wave = tid >> 6, wm = wave >> 2, wn = wave & 3;
  const long i0 = (long)blockIdx.x * 64;
  const uint32_t keyT = sc->keyT;
  const float Z = sc->Z;

  // per-thread weight source: chunk rows wn*32 + {ni*16 + l16}, K slice quad*8
  const u16* bsrc = wch + (size_t)((wn*32 + l16)*32 + quad*8);
  uint4 pA0 = *(const uint4*)(bsrc);               // chunk 0, ni=0
  uint4 pA1 = *(const uint4*)(bsrc + 512);         // chunk 0, ni=1
  uint4 pB0 = *(const uint4*)(bsrc + 4096);        // chunk 1
  uint4 pB1 = *(const uint4*)(bsrc + 4096 + 512);

  // ---- stage gX tile (64 x 512) into AF as bf16, g folded; row = lane; swizzled ----
  {
    int row = lane;
    long ir = i0 + row; if (ir >= NROWS) ir = NROWS - 1;
    float p = preds[ir];
    float pm = (fmono(p) <= keyT) ? 0.f : p;
    float g = 1.f + __expf(pm) / Z;
    const float4* src = (const float4*)(feats + ir*DD + wave*64);
    u16* dstrow = AF + row*512;
    const int swz = row & 7;
    #pragma unroll
    for (int j = 0; j < 8; ++j){
      float4 a = src[2*j], b = src[2*j + 1];
      uint4 pk;
      pk.x = pkbf(a.x*g, a.y*g); pk.y = pkbf(a.z*g, a.w*g);
      pk.z = pkbf(b.x*g, b.y*g); pk.w = pkbf(b.z*g, b.w*g);
      int blk = wave*8 + j;
      *(uint4*)&dstrow[(blk ^ swz) << 3] = pk;
    }
  }
  __syncthreads();   // AF visible to all waves

  const int sb = l16 & 7;
  const int base_a0 = (wm*32 + l16) * 512;
  const int base_a1 = base_a0 + 8192;          // +16 rows
  f32x4 acc[2][2];
  uint32_t pkF[4][8];
  int ci = 0;

#define KSTEP(P0, P1)                                                \
  {                                                                  \
    bf16x8 b0 = __builtin_bit_cast(bf16x8, P0);                      \
    bf16x8 b1 = __builtin_bit_cast(bf16x8, P1);                      \
    if (ci + 2 < 144){                                               \
      const u16* s_ = bsrc + (size_t)(ci + 2)*4096;                  \
      P0 = *(const uint4*)s_;                                        \
      P1 = *(const uint4*)(s_ + 512);                                \
    }                                                                \
    int abk = ((((ci & 15) << 2) | quad) ^ sb) << 3;                 \
    bf16x8 a0 = *(const bf16x8*)&AF[base_a0 + abk];                  \
    bf16x8 a1 = *(const bf16x8*)&AF[base_a1 + abk];                  \
    acc[0][0] = MFMA16(a0, b0, acc[0][0]);                           \
    acc[0][1] = MFMA16(a0, b1, acc[0][1]);                           \
    acc[1][0] = MFMA16(a1, b0, acc[1][0]);                           \
    acc[1][1] = MFMA16(a1, b1, acc[1][1]);                           \
    ++ci;                                                            \
  }

  // ---- stage 1: f = relu(gX @ Wl^T + bl) -> pkF registers (fully unrolled) ----
  #pragma unroll
  for (int nt = 0; nt < 4; ++nt){
    #pragma unroll
    for (int mi = 0; mi < 2; ++mi)
      #pragma unroll
      for (int ni = 0; ni < 2; ++ni) acc[mi][ni] = (f32x4){0.f,0.f,0.f,0.f};
    #pragma unroll
    for (int kh = 0; kh < 8; ++kh){
      KSTEP(pA0, pA1);
      KSTEP(pB0, pB1);
    }
    #pragma unroll
    for (int ni = 0; ni < 2; ++ni){
      float bb = bl[nt*128 + wn*32 + ni*16 + l16];
      #pragma unroll
      for (int mi = 0; mi < 2; ++mi){
        float e0 = acc[mi][ni][0] + bb; e0 = e0 > 0.f ? e0 : 0.f;
        float e1 = acc[mi][ni][1] + bb; e1 = e1 > 0.f ? e1 : 0.f;
        float e2 = acc[mi][ni][2] + bb; e2 = e2 > 0.f ? e2 : 0.f;
        float e3 = acc[mi][ni][3] + bb; e3 = e3 > 0.f ? e3 : 0.f;
        pkF[nt][mi*4 + ni*2 + 0] = pkbf(e0, e1);
        pkF[nt][mi*4 + ni*2 + 1] = pkbf(e2, e3);
      }
    }
  }

  __syncthreads();   // all stage-1 AF reads complete before overwrite
  // ---- transpose pkF (C-layout) -> F tile in AF (A-operand layout, swizzled) ----
  #pragma unroll
  for (int nt = 0; nt < 4; ++nt)
    #pragma unroll
    for (int mi = 0; mi < 2; ++mi)
      #pragma unroll
      for (int ni = 0; ni < 2; ++ni){
        int col = nt*128 + wn*32 + ni*16 + l16;
        int r0 = wm*32 + mi*16 + quad*4;
        uint32_t x = pkF[nt][mi*4 + ni*2], y = pkF[nt][mi*4 + ni*2 + 1];
        int cb = col >> 3, cw = col & 7;
        AF[(r0+0)*512 + ((cb ^ ((r0+0)&7)) << 3) + cw] = (u16)x;
        AF[(r0+1)*512 + ((cb ^ ((r0+1)&7)) << 3) + cw] = (u16)(x >> 16);
        AF[(r0+2)*512 + ((cb ^ ((r0+2)&7)) << 3) + cw] = (u16)y;
        AF[(r0+3)*512 + ((cb ^ ((r0+3)&7)) << 3) + cw] = (u16)(y >> 16);
      }
  __syncthreads();   // F tile visible

  // ---- stage 2: [Q|V] = f @ W^T ; Q first (nt2=0 -> e), then V weighted ----
  for (int nt2 = 0; nt2 < 5; ++nt2){
    #pragma unroll
    for (int mi = 0; mi < 2; ++mi)
      #pragma unroll
      for (int ni = 0; ni < 2; ++ni) acc[mi][ni] = (f32x4){0.f,0.f,0.f,0.f};
    #pragma unroll
    for (int kh = 0; kh < 8; ++kh){
      KSTEP(pA0, pA1);
      KSTEP(pB0, pB1);
    }
    if (nt2 == 0){
      // ---- Q epilogue: tanh, dot with qmv, e = exp(score/sqrt(128)) ----
      float p0[2][4], p1[2][4];
      #pragma unroll
      for (int mi = 0; mi < 2; ++mi)
        #pragma unroll
        for (int e = 0; e < 4; ++e){ p0[mi][e] = 0.f; p1[mi][e] = 0.f; }
      #pragma unroll
      for (int ni = 0; ni < 2; ++ni){
        int qc = wn*32 + ni*16 + l16;
        float bqv = bq[qc], q0 = qmv[qc], q1 = qmv[QD + qc];
        #pragma unroll
        for (int mi = 0; mi < 2; ++mi)
          #pragma unroll
          for (int e = 0; e < 4; ++e){
            float tq = tanhf(acc[mi][ni][e] + bqv);
            p0[mi][e] += tq * q0;
            p1[mi][e] += tq * q1;
          }
      }
      #pragma unroll
      for (int off = 1; off <= 8; off <<= 1)
        #pragma unroll
        for (int mi = 0; mi < 2; ++mi)
          #pragma unroll
          for (int e = 0; e < 4; ++e){
            p0[mi][e] += __shfl_xor(p0[mi][e], off);
            p1[mi][e] += __shfl_xor(p1[mi][e], off);
          }
      if (l16 == 0){
        #pragma unroll
        for (int mi = 0; mi < 2; ++mi)
          #pragma unroll
          for (int e = 0; e < 4; ++e){
            int row = wm*32 + mi*16 + quad*4 + e;
            sred[row*8 + 0*4 + wn] = p0[mi][e];
            sred[row*8 + 1*4 + wn] = p1[mi][e];
          }
      }
      __syncthreads();   // sred complete
      if (tid < 128){
        int row = tid >> 1, j = tid & 1;
        float sv = (sred[row*8 + j*4+0] + sred[row*8 + j*4+1] + sred[row*8 + j*4+2] + sred[row*8 + j*4+3])
                   * 0.08838834764831845f;
        bool valid = (i0 + row) < NROWS;
        float ev = valid ? __expf(sv) : 0.f;
        EfL[row*2 + j] = ev;
        if (valid) Aout[(i0 + row)*2 + j] = ev;
        float t2 = ev;
        #pragma unroll
        for (int off = 2; off <= 32; off <<= 1) t2 += __shfl_xor(t2, off);
        if (lane < 2) gpartE[(size_t)blockIdx.x*4 + (tid >> 6)*2 + j] = t2;
      }
      __syncthreads();   // EfL visible before V epilogues
    } else {
      // ---- V epilogue: e-weighted column sums (e from EfL) -> per-(block,wm) gpart ----
      float ef0[2][4], ef1[2][4];
      #pragma unroll
      for (int mi = 0; mi < 2; ++mi)
        #pragma unroll
        for (int e = 0; e < 4; ++e){
          int row = wm*32 + mi*16 + quad*4 + e;
          ef0[mi][e] = EfL[row*2 + 0];
          ef1[mi][e] = EfL[row*2 + 1];
        }
      #pragma unroll
      for (int ni = 0; ni < 2; ++ni){
        int colv = (nt2 - 1)*128 + wn*32 + ni*16 + l16;
        float bvv = bv[colv];
        float b0 = 0.f, b1 = 0.f;
        #pragma unroll
        for (int mi = 0; mi < 2; ++mi)
          #pragma unroll
          for (int e = 0; e < 4; ++e){
            float v = acc[mi][ni][e] + bvv;
            b0 += v * ef0[mi][e];
            b1 += v * ef1[mi][e];
          }
        b0 += __shfl_xor(b0, 16); b0 += __shfl_xor(b0, 32);
        b1 += __shfl_xor(b1, 16); b1 += __shfl_xor(b1, 32);
        if (quad == 0){
          gpart[((size_t)blockIdx.x*2 + wm)*1024 + colv]       = b0;
          gpart[((size_t)blockIdx.x*2 + wm)*1024 + 512 + colv] = b1;
        }
      }
    }
  }
#undef KSTEP
}

// ---------- k_red: parallel reduce -> sumEV[1024], sumE[2] ----------
__global__ void k_red(const float* __restrict__ gpart, const float* __restrict__ gpartE,
                      float* __restrict__ sumEV, float* __restrict__ sumE){
  const int t = threadIdx.x;
  if (blockIdx.x == 256){
    __shared__ float r0[256], r1[256];
    float s0 = 0.f, s1 = 0.f;
    for (int i = t; i < NB*2; i += 256){ s0 += gpartE[(size_t)i*2]; s1 += gpartE[(size_t)i*2 + 1]; }
    r0[t] = s0; r1[t] = s1;
    __syncthreads();
    for (int st = 128; st; st >>= 1){
      if (t < st){ r0[t] += r0[t + st]; r1[t] += r1[t + st]; }
      __syncthreads();
    }
    if (t == 0){ sumE[0] = r0[0]; sumE[1] = r1[0]; }
    return;
  }
  __shared__ float4 red[256];
  int col4 = blockIdx.x * 4;
  float4 s = {0.f, 0.f, 0.f, 0.f};
  for (int r = t; r < NB*2; r += 256){
    float4 v = *(const float4*)(gpart + (size_t)r*1024 + col4);
    s.x += v.x; s.y += v.y; s.z += v.z; s.w += v.w;
  }
  red[t] = s;
  __syncthreads();
  for (int st = 128; st; st >>= 1){
    if (t < st){
      float4 o = red[t + st];
      red[t].x += o.x; red[t].y += o.y; red[t].z += o.z; red[t].w += o.w;
    }
    __syncthreads();
  }
  if (t == 0) *(float4*)(sumEV + col4) = red[0];
}

// ---------- k_post: normalize A; compute B and Cout ----------
__global__ void k_post(float* __restrict__ out, const float* __restrict__ sumE,
                       const float* __restrict__ sumEV, const float* __restrict__ Wfcc,
                       const float* __restrict__ bfcc){
  if (blockIdx.x < 782){
    int idx = blockIdx.x*256 + threadIdx.x;
    if (idx < 200000) out[2 + idx] = out[2 + idx] / sumE[idx & 1];
    return;
  }
  __shared__ float red[512];
  int t = threadIdx.x;
  float z0 = sumE[0], z1 = sumE[1];
  float c0 = 0.f, c1 = 0.f;
  for (int e = t; e < 1024; e += 256){
    float bvv = sumEV[e] / ((e >> 9) ? z1 : z0);
    out[200002 + e] = bvv;
    c0 += bvv * Wfcc[e];
    c1 += bvv * Wfcc[1024 + e];
  }
  red[t] = c0; red[256 + t] = c1;
  __syncthreads();
  for (int s = 128; s; s >>= 1){
    if (t < s){ red[t] += red[t + s]; red[256 + t] += red[256 + t + s]; }
    __syncthreads();
  }
  if (t == 0){ out[0] = red[0] + bfcc[0]; out[1] = red[256] + bfcc[1]; }
}

// ---------- launch ----------
extern "C" void kernel_launch(void* const* d_in, const int* in_sizes, int n_in,
                              void* d_out, int out_size, void* d_ws, size_t ws_size,
                              hipStream_t stream){
  (void)in_sizes; (void)n_in; (void)out_size; (void)ws_size;
  const float* feats = (const float*)d_in[0];
  const float* c     = (const float*)d_in[1];
  const float* preds = (const float*)d_in[2];
  const float* W_lin = (const float*)d_in[3];
  const float* b_lin = (const float*)d_in[4];
  const float* W_q   = (const float*)d_in[5];
  const float* b_q   = (const float*)d_in[6];
  const float* W_v   = (const float*)d_in[7];
  const float* b_v   = (const float*)d_in[8];
  const float* W_fcc = (const float*)d_in[9];
  const float* b_fcc = (const float*)d_in[10];
  float* out = (float*)d_out;
  char* ws = (char*)d_ws;

  // ws layout (bytes) — every region fully rewritten each call
  u16*   wch    = (u16*)(ws + 0);            // 1179648 (144 chunks x 8KB)
  Scal*  sc     = (Scal*)(ws + 1179648);     // 64       -> 1179712
  float* qmv    = (float*)(ws + 1179712);    // 1024     -> 1180736
  float* sumE   = (float*)(ws + 1180736);    // 64       -> 1180800
  float* sumEV  = (float*)(ws + 1180800);    // 4096     -> 1184896
  float* fmFw   = (float*)(ws + 1184896);    // 4096     -> 1188992
  float* gpartE = (float*)(ws + 1188992);    // 25088    -> 1214080
  float* gpart  = (float*)(ws + 1214080);    // 1563*2*1024*4 = 12804096 -> 14018176
  // prep-phase scratch OVERLAYS gpart (gpart is written only later, by k_fused)
  uint32_t* hist = (uint32_t*)(ws + 1214080);          // 4096*4 = 16384
  ull*      cmax = (ull*)(ws + 1214080 + 16384);       // 16

  k_conv <<<2304, 256, 0, stream>>>(W_lin, W_v, W_q, wch, hist, cmax);
  k_sel1 <<<256, 256, 0, stream>>>(preds, c, hist, cmax);
  k_prep2<<<1, 1024, 0, stream>>>(preds, hist, sc);
  k_prep3<<<16, 256, 0, stream>>>(preds, feats, W_lin, b_lin, cmax, sc, fmFw);
  k_prep4<<<2, 256, 0, stream>>>(W_q, b_q, fmFw, qmv);
  k_fused<<<NB, 512, 0, stream>>>(feats, preds, wch, b_lin, b_v, b_q,
                                  qmv, sc, gpart, gpartE, out + 2);
  k_red  <<<257, 256, 0, stream>>>(gpart, gpartE, sumEV, sumE);
  k_post <<<783, 256, 0, stream>>>(out, sumE, sumEV, W_fcc, b_fcc);
}

// Round 7
// 706.990 us; speedup vs baseline: 1.2091x; 1.2091x over previous
//
#include <hip/hip_runtime.h>
#include <stdint.h>

typedef unsigned short u16;
typedef __bf16 bf16t;
typedef bf16t bf16x8 __attribute__((ext_vector_type(8)));
typedef float f32x4 __attribute__((ext_vector_type(4)));
typedef unsigned long long ull;

#define NROWS 100000
#define DD 512
#define QD 128
#define KSEL 20000
#define NB 1563   // ceil(100000/64)
#define NBINS 4096

// ---------- helpers ----------
__device__ __forceinline__ uint32_t fmono(float x){
  uint32_t u = __float_as_uint(x);
  return (u & 0x80000000u) ? ~u : (u | 0x80000000u);
}
__device__ __forceinline__ float finv(uint32_t k){  // inverse of fmono
  uint32_t u = (k & 0x80000000u) ? (k & 0x7fffffffu) : ~k;
  return __uint_as_float(u);
}
__device__ __forceinline__ u16 f2bf(float x){  // RNE float->bf16 bits
  uint32_t u = __float_as_uint(x);
  u += 0x7fffu + ((u >> 16) & 1u);
  return (u16)(u >> 16);
}
__device__ __forceinline__ uint32_t pkbf(float a, float b){
  return (uint32_t)f2bf(a) | ((uint32_t)f2bf(b) << 16);
}

struct Scal {
  uint32_t keyT;
  float Z;
  uint32_t pad[14];
};

#define MFMA16(A,B,C) __builtin_amdgcn_mfma_f32_16x16x32_bf16(A,B,C,0,0,0)

// ---------- k_conv: fp32 weights -> bf16 chunk-format; zero hist / cmax ----------
// Chunk ci (0..143) = 128 output-rows x 32 K-cols, contiguous (4096 u16):
// elem = ci*4096 + r*32 + col.  Stage1: ci = nt*16+kc (Wl). Stage2: 64 + nt2*16+kc (Wq then Wv).
__global__ void k_conv(const float* __restrict__ Wl, const float* __restrict__ Wv,
                       const float* __restrict__ Wq, u16* __restrict__ wch,
                       uint32_t* __restrict__ hist, ull* __restrict__ cmax){
  int idx = blockIdx.x*256 + threadIdx.x;          // grid 2304*256 = 589824 exactly
  if (idx < NBINS) hist[idx] = 0u;
  if (idx == 0){ cmax[0] = 0ull; cmax[1] = 0ull; }
  int ci  = idx >> 12;
  int rem = idx & 4095;
  int r   = rem >> 5;
  int col = rem & 31;
  float v;
  if (ci < 64){
    int nt = ci >> 4, kc = ci & 15;
    v = Wl[(size_t)(nt*128 + r)*DD + kc*32 + col];
  } else {
    int c2 = ci - 64;
    int nt2 = c2 >> 4, kc = c2 & 15;
    if (nt2 == 0) v = Wq[(size_t)r*DD + kc*32 + col];
    else          v = Wv[(size_t)((nt2-1)*128 + r)*DD + kc*32 + col];
  }
  wch[idx] = f2bf(v);
}

// ---------- k_sel1: multi-block 12-bit histogram of fmono(preds) + c-argmax partials ----------
__global__ void k_sel1(const float* __restrict__ preds, const float* __restrict__ c,
                       uint32_t* __restrict__ hist, ull* __restrict__ cmax){
  __shared__ ull kr0[4], kr1[4];
  const int t = threadIdx.x;                // 256
  const int gid = blockIdx.x*256 + t;       // grid 256 blocks -> 65536 threads
  const int lane = t & 63;

  const float4* p4 = (const float4*)preds;
  for (int i = gid; i < 25000; i += 65536){
    float4 v = p4[i];
    atomicAdd(&hist[fmono(v.x) >> 20], 1u);
    atomicAdd(&hist[fmono(v.y) >> 20], 1u);
    atomicAdd(&hist[fmono(v.z) >> 20], 1u);
    atomicAdd(&hist[fmono(v.w) >> 20], 1u);
  }

  ull k0 = 0ull, k1 = 0ull;
  const float4* c4 = (const float4*)c;
  for (int i = gid; i < 50000; i += 65536){
    float4 v = c4[i];                       // rows 2i (x=c0,y=c1), 2i+1 (z=c0,w=c1)
    uint32_t r0 = 2u*i, r1 = 2u*i + 1u;
    ull a0 = ((ull)fmono(v.x) << 32) | (ull)(~r0);
    ull a1 = ((ull)fmono(v.z) << 32) | (ull)(~r1);
    ull b0 = ((ull)fmono(v.y) << 32) | (ull)(~r0);
    ull b1 = ((ull)fmono(v.w) << 32) | (ull)(~r1);
    if (a0 > k0) k0 = a0;
    if (a1 > k0) k0 = a1;
    if (b0 > k1) k1 = b0;
    if (b1 > k1) k1 = b1;
  }
  #pragma unroll
  for (int off = 32; off; off >>= 1){
    ull o0 = __shfl_xor(k0, off); if (o0 > k0) k0 = o0;
    ull o1 = __shfl_xor(k1, off); if (o1 > k1) k1 = o1;
  }
  if (lane == 0){ kr0[t >> 6] = k0; kr1[t >> 6] = k1; }
  __syncthreads();
  if (t == 0){
    ull m0 = kr0[0], m1 = kr1[0];
    #pragma unroll
    for (int w = 1; w < 4; ++w){
      if (kr0[w] > m0) m0 = kr0[w];
      if (kr1[w] > m1) m1 = kr1[w];
    }
    atomicMax(&cmax[0], m0);
    atomicMax(&cmax[1], m1);
  }
}

// ---------- k_prep2: one block — scan hist, exact keyT, Z ----------
#define CAND_CAP 8192
__launch_bounds__(1024)
__global__ void k_prep2(const float* __restrict__ preds,
                        const uint32_t* __restrict__ hist,
                        Scal* __restrict__ sc){
  __shared__ uint32_t cand[CAND_CAP];
  __shared__ uint32_t wsum[16], woff[16];
  __shared__ float zred[16];
  __shared__ uint32_t s_B, s_cumBelow, s_keyT, candN;
  const int t = threadIdx.x;
  const int lane = t & 63, wv = t >> 6;

  if (t == 0) candN = 0;

  // ---- parallel scan of 4096-bin histogram; find bucket containing rank KSEL ----
  const int b0 = t*4;
  uint4 hv = ((const uint4*)hist)[t];
  uint32_t local = hv.x + hv.y + hv.z + hv.w;
  uint32_t x = local;
  #pragma unroll
  for (int off = 1; off < 64; off <<= 1){
    uint32_t y = __shfl_up(x, off);
    if (lane >= off) x += y;
  }
  if (lane == 63) wsum[wv] = x;
  __syncthreads();
  if (t == 0){
    uint32_t cum = 0;
    for (int w = 0; w < 16; ++w){ woff[w] = cum; cum += wsum[w]; }
  }
  __syncthreads();
  uint32_t excl = x - local + woff[wv];       // exclusive prefix of this thread's 4 bins
  if (excl < KSEL && excl + local >= KSEL){   // unique crossing thread
    uint32_t cum = excl;
    uint32_t hh[4] = {hv.x, hv.y, hv.z, hv.w};
    #pragma unroll
    for (int b = 0; b < 4; ++b){
      if (cum + hh[b] >= KSEL){ s_B = (uint32_t)(b0 + b); s_cumBelow = cum; break; }
      cum += hh[b];
    }
  }
  __syncthreads();
  const uint32_t B = s_B;

  // ---- one pass over preds: sum exp over buckets > B; collect bucket-B candidates ----
  float sA = 0.f;
  const float4* p4 = (const float4*)preds;
  for (int i = t; i < 25000; i += 1024){
    float4 v = p4[i];
    float vv[4] = {v.x, v.y, v.z, v.w};
    #pragma unroll
    for (int e = 0; e < 4; ++e){
      uint32_t k = fmono(vv[e]);
      uint32_t bb = k >> 20;
      if (bb > B){
        sA += __expf(vv[e]);
      } else if (bb == B){
        uint32_t idx = atomicAdd(&candN, 1u);
        if (idx < CAND_CAP) cand[idx] = k;
      }
    }
  }
  #pragma unroll
  for (int off = 32; off; off >>= 1) sA += __shfl_xor(sA, off);
  if (lane == 0) zred[wv] = sA;
  __syncthreads();

  // ---- exact rank select among candidates (O(n^2), n ~ a thousand) ----
  const uint32_t n = candN < CAND_CAP ? candN : CAND_CAP;
  const uint32_t r = KSEL - s_cumBelow;       // 1-indexed rank within bucket
  for (uint32_t i = t; i < n; i += 1024){
    uint32_t ki = cand[i];
    uint32_t less = 0, eq = 0;
    for (uint32_t j = 0; j < n; ++j){
      uint32_t kj = cand[j];
      less += (kj < ki) ? 1u : 0u;
      eq   += (kj == ki) ? 1u : 0u;
    }
    if (less < r && r <= less + eq) s_keyT = ki;
  }
  __syncthreads();
  const uint32_t keyT = s_keyT;

  // ---- add exp of candidates strictly above keyT ----
  float sCA = 0.f;
  for (uint32_t i = t; i < n; i += 1024){
    uint32_t k = cand[i];
    if (k > keyT) sCA += __expf(finv(k));
  }
  #pragma unroll
  for (int off = 32; off; off >>= 1) sCA += __shfl_xor(sCA, off);
  if (lane == 0) zred[wv] += sCA;
  __syncthreads();
  if (t == 0){
    float Z = (float)KSEL;                    // exp(0)=1 for each of the KSEL zeroed entries
    for (int w = 0; w < 16; ++w) Z += zred[w];
    sc->keyT = keyT; sc->Z = Z;
  }
}

// ---------- k_prep3: 16 blocks — exact fp32 m_feats (f rows for the 2 argmax rows) ----------
__global__ void k_prep3(const float* __restrict__ preds, const float* __restrict__ feats,
                        const float* __restrict__ Wl, const float* __restrict__ bl,
                        const ull* __restrict__ cmax, const Scal* __restrict__ sc,
                        float* __restrict__ fmFw){
  __shared__ float fmX[2][512];
  __shared__ uint32_t s_mi[2];
  const int t = threadIdx.x;   // 256
  if (t < 2) s_mi[t] = ~(uint32_t)(cmax[t] & 0xffffffffull);
  __syncthreads();
  for (int i = t; i < 1024; i += 256){
    int j = i >> 9, col = i & 511;
    fmX[j][col] = feats[(size_t)s_mi[j]*DD + col];
  }
  __syncthreads();
  const int nn = blockIdx.x*32 + (t >> 3);
  const int h = t & 7;
  const float4* wr4 = (const float4*)(Wl + (size_t)nn*DD + h*64);
  const float4* x04 = (const float4*)(&fmX[0][h*64]);
  const float4* x14 = (const float4*)(&fmX[1][h*64]);
  float a0 = 0.f, a1 = 0.f;
  #pragma unroll
  for (int k = 0; k < 16; ++k){
    float4 w = wr4[k], u = x04[k], v = x14[k];
    a0 += u.x*w.x + u.y*w.y + u.z*w.z + u.w*w.w;
    a1 += v.x*w.x + v.y*w.y + v.z*w.z + v.w*w.w;
  }
  a0 += __shfl_xor(a0, 1); a0 += __shfl_xor(a0, 2); a0 += __shfl_xor(a0, 4);
  a1 += __shfl_xor(a1, 1); a1 += __shfl_xor(a1, 2); a1 += __shfl_xor(a1, 4);
  if (h == 0){
    uint32_t keyT = sc->keyT;
    float Z = sc->Z;
    float p0 = preds[s_mi[0]]; float q0 = (fmono(p0) <= keyT) ? 0.f : p0;
    float g0 = 1.f + __expf(q0) / Z;
    float p1 = preds[s_mi[1]]; float q1 = (fmono(p1) <= keyT) ? 0.f : p1;
    float g1 = 1.f + __expf(q1) / Z;
    float v0 = bl[nn] + g0*a0; fmFw[nn]       = v0 > 0.f ? v0 : 0.f;
    float v1 = bl[nn] + g1*a1; fmFw[512 + nn] = v1 > 0.f ? v1 : 0.f;
  }
}

// ---------- k_prep4: 2 blocks — q_max ----------
__global__ void k_prep4(const float* __restrict__ Wq, const float* __restrict__ bq,
                        const float* __restrict__ fmFw, float* __restrict__ qmv){
  __shared__ float xs[512];
  const int t = threadIdx.x;   // 256
  const int j = blockIdx.x;
  for (int i = t; i < 512; i += 256) xs[i] = fmFw[j*512 + i];
  __syncthreads();
  const int q = t >> 1, h = t & 1;
  const float4* wr4 = (const float4*)(Wq + (size_t)q*DD + h*256);
  const float4* x4  = (const float4*)(&xs[h*256]);
  float a = 0.f;
  #pragma unroll 4
  for (int k = 0; k < 64; ++k){
    float4 w = wr4[k], u = x4[k];
    a += u.x*w.x + u.y*w.y + u.z*w.z + u.w*w.w;
  }
  a += __shfl_xor(a, 1);
  if (h == 0) qmv[j*QD + q] = tanhf(bq[q] + a);
}

// ---------- k_fused v7: 256 threads / 4 waves, wave tile 64x32 (R3 shape);
// barrier-free K-loop, B from L2 with 4-deep chunk prefetch, A in swizzled LDS.
// Stage-1 fully unrolled -> pkF[4][16] static (registers, no rule-#20 scratch).
// EfL in LDS (no eR register arrays). LDS 68096B -> 2 blocks/CU.
__launch_bounds__(256, 2)
__global__ void k_fused(const float* __restrict__ feats, const float* __restrict__ preds,
                        const u16* __restrict__ wch,
                        const float* __restrict__ bl, const float* __restrict__ bv,
                        const float* __restrict__ bq, const float* __restrict__ qmv,
                        const Scal* __restrict__ sc,
                        float* __restrict__ gpart, float* __restrict__ gpartE,
                        float* __restrict__ Aout){
  __shared__ __align__(16) u16 AF[32768];    // [64][512]
  __shared__ __align__(16) float sred[512];  // [64 rows][2 j][4 waves]
  __shared__ __align__(16) float EfL[128];   // e-values [64 rows][2 j]
  const int tid = threadIdx.x;
  const int lane = tid & 63, quad = lane >> 4, l16 = lane & 15;
  const int wave = tid >> 6;                 // wn = wave, 0..3
  const long i0 = (long)blockIdx.x * 64;
  const uint32_t keyT = sc->keyT;
  const float Z = sc->Z;

  // per-thread weight source: chunk rows wave*32 + {l16, 16+l16}, K slice quad*8
  const u16* bsrc = wch + (size_t)((wave*32 + l16)*32 + quad*8);
  uint4 pA0 = *(const uint4*)(bsrc);                 // chunk 0
  uint4 pA1 = *(const uint4*)(bsrc + 512);
  uint4 pB0 = *(const uint4*)(bsrc + 4096);          // chunk 1
  uint4 pB1 = *(const uint4*)(bsrc + 4096 + 512);
  uint4 pC0 = *(const uint4*)(bsrc + 8192);          // chunk 2
  uint4 pC1 = *(const uint4*)(bsrc + 8192 + 512);
  uint4 pD0 = *(const uint4*)(bsrc + 12288);         // chunk 3
  uint4 pD1 = *(const uint4*)(bsrc + 12288 + 512);

  // ---- stage gX tile (64 x 512) into AF as bf16, g folded; row = lane; swizzled ----
  {
    int row = lane;
    long ir = i0 + row; if (ir >= NROWS) ir = NROWS - 1;
    float p = preds[ir];
    float pm = (fmono(p) <= keyT) ? 0.f : p;
    float g = 1.f + __expf(pm) / Z;
    const float4* src = (const float4*)(feats + ir*DD + wave*128);
    u16* dstrow = AF + row*512;
    const int swz = row & 7;
    #pragma unroll
    for (int j = 0; j < 16; ++j){
      float4 a = src[2*j], b = src[2*j + 1];
      uint4 pk;
      pk.x = pkbf(a.x*g, a.y*g); pk.y = pkbf(a.z*g, a.w*g);
      pk.z = pkbf(b.x*g, b.y*g); pk.w = pkbf(b.z*g, b.w*g);
      int blk = (wave << 4) | j;
      *(uint4*)&dstrow[(blk ^ swz) << 3] = pk;
    }
  }
  __syncthreads();   // AF visible to all waves

  const int sb = l16 & 7;
  const int ba0 = l16 * 512;
  const int ba1 = ba0 + 8192;    // +16 rows
  const int ba2 = ba0 + 16384;   // +32 rows
  const int ba3 = ba0 + 24576;   // +48 rows
  f32x4 acc[4][2];
  uint32_t pkF[4][16];
  int ci = 0;

#define KSTEP(P0, P1)                                                \
  {                                                                  \
    bf16x8 b0 = __builtin_bit_cast(bf16x8, P0);                      \
    bf16x8 b1 = __builtin_bit_cast(bf16x8, P1);                      \
    if (ci + 4 < 144){                                               \
      const u16* s_ = bsrc + (size_t)(ci + 4)*4096;                  \
      P0 = *(const uint4*)s_;                                        \
      P1 = *(const uint4*)(s_ + 512);                                \
    }                                                                \
    int abk = ((((ci & 15) << 2) | quad) ^ sb) << 3;                 \
    bf16x8 a0 = *(const bf16x8*)&AF[ba0 + abk];                      \
    bf16x8 a1 = *(const bf16x8*)&AF[ba1 + abk];                      \
    bf16x8 a2 = *(const bf16x8*)&AF[ba2 + abk];                      \
    bf16x8 a3 = *(const bf16x8*)&AF[ba3 + abk];                      \
    acc[0][0] = MFMA16(a0, b0, acc[0][0]);                           \
    acc[0][1] = MFMA16(a0, b1, acc[0][1]);                           \
    acc[1][0] = MFMA16(a1, b0, acc[1][0]);                           \
    acc[1][1] = MFMA16(a1, b1, acc[1][1]);                           \
    acc[2][0] = MFMA16(a2, b0, acc[2][0]);                           \
    acc[2][1] = MFMA16(a2, b1, acc[2][1]);                           \
    acc[3][0] = MFMA16(a3, b0, acc[3][0]);                           \
    acc[3][1] = MFMA16(a3, b1, acc[3][1]);                           \
    ++ci;                                                            \
  }

  // ---- stage 1: f = relu(gX @ Wl^T + bl) -> pkF registers (fully unrolled) ----
  #pragma unroll
  for (int nt = 0; nt < 4; ++nt){
    #pragma unroll
    for (int mi = 0; mi < 4; ++mi)
      #pragma unroll
      for (int ni = 0; ni < 2; ++ni) acc[mi][ni] = (f32x4){0.f,0.f,0.f,0.f};
    #pragma unroll
    for (int kh = 0; kh < 4; ++kh){
      KSTEP(pA0, pA1);
      KSTEP(pB0, pB1);
      KSTEP(pC0, pC1);
      KSTEP(pD0, pD1);
    }
    #pragma unroll
    for (int ni = 0; ni < 2; ++ni){
      float bb = bl[nt*128 + wave*32 + ni*16 + l16];
      #pragma unroll
      for (int mi = 0; mi < 4; ++mi){
        float e0 = acc[mi][ni][0] + bb; e0 = e0 > 0.f ? e0 : 0.f;
        float e1 = acc[mi][ni][1] + bb; e1 = e1 > 0.f ? e1 : 0.f;
        float e2 = acc[mi][ni][2] + bb; e2 = e2 > 0.f ? e2 : 0.f;
        float e3 = acc[mi][ni][3] + bb; e3 = e3 > 0.f ? e3 : 0.f;
        pkF[nt][mi*4 + ni*2 + 0] = pkbf(e0, e1);
        pkF[nt][mi*4 + ni*2 + 1] = pkbf(e2, e3);
      }
    }
  }

  __syncthreads();   // all stage-1 AF reads complete before overwrite
  // ---- transpose pkF (C-layout) -> F tile in AF (A-operand layout, swizzled) ----
  #pragma unroll
  for (int nt = 0; nt < 4; ++nt)
    #pragma unroll
    for (int mi = 0; mi < 4; ++mi)
      #pragma unroll
      for (int ni = 0; ni < 2; ++ni){
        int col = nt*128 + wave*32 + ni*16 + l16;
        int r0 = mi*16 + quad*4;
        uint32_t x = pkF[nt][mi*4 + ni*2], y = pkF[nt][mi*4 + ni*2 + 1];
        int cb = col >> 3, cw = col & 7;
        AF[(r0+0)*512 + ((cb ^ ((r0+0)&7)) << 3) + cw] = (u16)x;
        AF[(r0+1)*512 + ((cb ^ ((r0+1)&7)) << 3) + cw] = (u16)(x >> 16);
        AF[(r0+2)*512 + ((cb ^ ((r0+2)&7)) << 3) + cw] = (u16)y;
        AF[(r0+3)*512 + ((cb ^ ((r0+3)&7)) << 3) + cw] = (u16)(y >> 16);
      }
  __syncthreads();   // F tile visible

  // ---- stage 2: [Q|V] = f @ W^T ; Q first (nt2=0 -> e), then V weighted ----
  for (int nt2 = 0; nt2 < 5; ++nt2){
    #pragma unroll
    for (int mi = 0; mi < 4; ++mi)
      #pragma unroll
      for (int ni = 0; ni < 2; ++ni) acc[mi][ni] = (f32x4){0.f,0.f,0.f,0.f};
    #pragma unroll
    for (int kh = 0; kh < 4; ++kh){
      KSTEP(pA0, pA1);
      KSTEP(pB0, pB1);
      KSTEP(pC0, pC1);
      KSTEP(pD0, pD1);
    }
    if (nt2 == 0){
      // ---- Q epilogue: tanh, dot with qmv, e = exp(score/sqrt(128)) ----
      float p0[4][4], p1[4][4];
      #pragma unroll
      for (int mi = 0; mi < 4; ++mi)
        #pragma unroll
        for (int e = 0; e < 4; ++e){ p0[mi][e] = 0.f; p1[mi][e] = 0.f; }
      #pragma unroll
      for (int ni = 0; ni < 2; ++ni){
        int qc = wave*32 + ni*16 + l16;
        float bqv = bq[qc], q0 = qmv[qc], q1 = qmv[QD + qc];
        #pragma unroll
        for (int mi = 0; mi < 4; ++mi)
          #pragma unroll
          for (int e = 0; e < 4; ++e){
            float tq = tanhf(acc[mi][ni][e] + bqv);
            p0[mi][e] += tq * q0;
            p1[mi][e] += tq * q1;
          }
      }
      #pragma unroll
      for (int off = 1; off <= 8; off <<= 1)
        #pragma unroll
        for (int mi = 0; mi < 4; ++mi)
          #pragma unroll
          for (int e = 0; e < 4; ++e){
            p0[mi][e] += __shfl_xor(p0[mi][e], off);
            p1[mi][e] += __shfl_xor(p1[mi][e], off);
          }
      if (l16 == 0){
        #pragma unroll
        for (int mi = 0; mi < 4; ++mi)
          #pragma unroll
          for (int e = 0; e < 4; ++e){
            int row = mi*16 + quad*4 + e;
            sred[row*8 + 0*4 + wave] = p0[mi][e];
            sred[row*8 + 1*4 + wave] = p1[mi][e];
          }
      }
      __syncthreads();   // sred complete
      if (tid < 128){
        int row = tid >> 1, j = tid & 1;
        float sv = (sred[row*8 + j*4+0] + sred[row*8 + j*4+1] + sred[row*8 + j*4+2] + sred[row*8 + j*4+3])
                   * 0.08838834764831845f;
        bool valid = (i0 + row) < NROWS;
        float ev = valid ? __expf(sv) : 0.f;
        EfL[row*2 + j] = ev;
        if (valid) Aout[(i0 + row)*2 + j] = ev;
        float t2 = ev;
        #pragma unroll
        for (int off = 2; off <= 32; off <<= 1) t2 += __shfl_xor(t2, off);
        if (lane < 2) gpartE[(size_t)blockIdx.x*4 + (tid >> 6)*2 + j] = t2;
      }
      __syncthreads();   // EfL visible before V epilogues
    } else {
      // ---- V epilogue: e-weighted column sums (e from EfL) -> per-block gpart ----
      float ef0[4][4], ef1[4][4];
      #pragma unroll
      for (int mi = 0; mi < 4; ++mi)
        #pragma unroll
        for (int e = 0; e < 4; ++e){
          int row = mi*16 + quad*4 + e;
          ef0[mi][e] = EfL[row*2 + 0];
          ef1[mi][e] = EfL[row*2 + 1];
        }
      #pragma unroll
      for (int ni = 0; ni < 2; ++ni){
        int colv = (nt2 - 1)*128 + wave*32 + ni*16 + l16;
        float bvv = bv[colv];
        float b0 = 0.f, b1 = 0.f;
        #pragma unroll
        for (int mi = 0; mi < 4; ++mi)
          #pragma unroll
          for (int e = 0; e < 4; ++e){
            float v = acc[mi][ni][e] + bvv;
            b0 += v * ef0[mi][e];
            b1 += v * ef1[mi][e];
          }
        b0 += __shfl_xor(b0, 16); b0 += __shfl_xor(b0, 32);
        b1 += __shfl_xor(b1, 16); b1 += __shfl_xor(b1, 32);
        if (quad == 0){
          gpart[(size_t)blockIdx.x*1024 + colv]       = b0;
          gpart[(size_t)blockIdx.x*1024 + 512 + colv] = b1;
        }
      }
    }
  }
#undef KSTEP
}

// ---------- k_red: parallel reduce -> sumEV[1024], sumE[2] ----------
__global__ void k_red(const float* __restrict__ gpart, const float* __restrict__ gpartE,
                      float* __restrict__ sumEV, float* __restrict__ sumE){
  const int t = threadIdx.x;
  if (blockIdx.x == 256){
    __shared__ float r0[256], r1[256];
    float s0 = 0.f, s1 = 0.f;
    for (int i = t; i < NB*2; i += 256){ s0 += gpartE[(size_t)i*2]; s1 += gpartE[(size_t)i*2 + 1]; }
    r0[t] = s0; r1[t] = s1;
    __syncthreads();
    for (int st = 128; st; st >>= 1){
      if (t < st){ r0[t] += r0[t + st]; r1[t] += r1[t + st]; }
      __syncthreads();
    }
    if (t == 0){ sumE[0] = r0[0]; sumE[1] = r1[0]; }
    return;
  }
  __shared__ float4 red[256];
  int col4 = blockIdx.x * 4;
  float4 s = {0.f, 0.f, 0.f, 0.f};
  for (int r = t; r < NB; r += 256){
    float4 v = *(const float4*)(gpart + (size_t)r*1024 + col4);
    s.x += v.x; s.y += v.y; s.z += v.z; s.w += v.w;
  }
  red[t] = s;
  __syncthreads();
  for (int st = 128; st; st >>= 1){
    if (t < st){
      float4 o = red[t + st];
      red[t].x += o.x; red[t].y += o.y; red[t].z += o.z; red[t].w += o.w;
    }
    __syncthreads();
  }
  if (t == 0) *(float4*)(sumEV + col4) = red[0];
}

// ---------- k_post: normalize A; compute B and Cout ----------
__global__ void k_post(float* __restrict__ out, const float* __restrict__ sumE,
                       const float* __restrict__ sumEV, const float* __restrict__ Wfcc,
                       const float* __restrict__ bfcc){
  if (blockIdx.x < 782){
    int idx = blockIdx.x*256 + threadIdx.x;
    if (idx < 200000) out[2 + idx] = out[2 + idx] / sumE[idx & 1];
    return;
  }
  __shared__ float red[512];
  int t = threadIdx.x;
  float z0 = sumE[0], z1 = sumE[1];
  float c0 = 0.f, c1 = 0.f;
  for (int e = t; e < 1024; e += 256){
    float bvv = sumEV[e] / ((e >> 9) ? z1 : z0);
    out[200002 + e] = bvv;
    c0 += bvv * Wfcc[e];
    c1 += bvv * Wfcc[1024 + e];
  }
  red[t] = c0; red[256 + t] = c1;
  __syncthreads();
  for (int s = 128; s; s >>= 1){
    if (t < s){ red[t] += red[t + s]; red[256 + t] += red[256 + t + s]; }
    __syncthreads();
  }
  if (t == 0){ out[0] = red[0] + bfcc[0]; out[1] = red[256] + bfcc[1]; }
}

// ---------- launch ----------
extern "C" void kernel_launch(void* const* d_in, const int* in_sizes, int n_in,
                              void* d_out, int out_size, void* d_ws, size_t ws_size,
                              hipStream_t stream){
  (void)in_sizes; (void)n_in; (void)out_size; (void)ws_size;
  const float* feats = (const float*)d_in[0];
  const float* c     = (const float*)d_in[1];
  const float* preds = (const float*)d_in[2];
  const float* W_lin = (const float*)d_in[3];
  const float* b_lin = (const float*)d_in[4];
  const float* W_q   = (const float*)d_in[5];
  const float* b_q   = (const float*)d_in[6];
  const float* W_v   = (const float*)d_in[7];
  const float* b_v   = (const float*)d_in[8];
  const float* W_fcc = (const float*)d_in[9];
  const float* b_fcc = (const float*)d_in[10];
  float* out = (float*)d_out;
  char* ws = (char*)d_ws;

  // ws layout (bytes) — every region fully rewritten each call
  u16*   wch    = (u16*)(ws + 0);            // 1179648 (144 chunks x 8KB)
  Scal*  sc     = (Scal*)(ws + 1179648);     // 64       -> 1179712
  float* qmv    = (float*)(ws + 1179712);    // 1024     -> 1180736
  float* sumE   = (float*)(ws + 1180736);    // 64       -> 1180800
  float* sumEV  = (float*)(ws + 1180800);    // 4096     -> 1184896
  float* fmFw   = (float*)(ws + 1184896);    // 4096     -> 1188992
  float* gpartE = (float*)(ws + 1188992);    // 25088    -> 1214080
  float* gpart  = (float*)(ws + 1214080);    // 1563*1024*4 = 6402048 -> 7616128
  // prep-phase scratch OVERLAYS gpart (gpart is written only later, by k_fused)
  uint32_t* hist = (uint32_t*)(ws + 1214080);          // 4096*4 = 16384
  ull*      cmax = (ull*)(ws + 1214080 + 16384);       // 16

  k_conv <<<2304, 256, 0, stream>>>(W_lin, W_v, W_q, wch, hist, cmax);
  k_sel1 <<<256, 256, 0, stream>>>(preds, c, hist, cmax);
  k_prep2<<<1, 1024, 0, stream>>>(preds, hist, sc);
  k_prep3<<<16, 256, 0, stream>>>(preds, feats, W_lin, b_lin, cmax, sc, fmFw);
  k_prep4<<<2, 256, 0, stream>>>(W_q, b_q, fmFw, qmv);
  k_fused<<<NB, 256, 0, stream>>>(feats, preds, wch, b_lin, b_v, b_q,
                                  qmv, sc, gpart, gpartE, out + 2);
  k_red  <<<257, 256, 0, stream>>>(gpart, gpartE, sumEV, sumE);
  k_post <<<783, 256, 0, stream>>>(out, sumE, sumEV, W_fcc, b_fcc);
}